// Round 1
// 324.761 us; speedup vs baseline: 1.0048x; 1.0048x over previous
//
#include <hip/hip_runtime.h>

// EmbeddingBag(mean): V=1e6, D=64, B=16384, L=50.
//
// R1 (this session): restructure from {64 lanes/bag + shfl index distribution +
// xor-tree reduce} to {16 lanes/bag, 4 bags/wave, LDS-staged indices}.
// Rationale: timed dur (326us) = ~156us in-graph poison fill (harness floor,
// visible as the 1.024GB fillBufferAligned dispatches at 6.6TB/s) + ~165us
// kernel. Kernel gathers 210MB of random 256B rows at only ~1.3TB/s effective.
// Concurrency math rules out simple latency-boundedness, so this version
// removes all cross-lane ops from the gather critical path:
//   - indices staged to LDS once per block (coalesced), read back via
//     conflict-free broadcast (layout padded to 65 words so the 4 groups of a
//     wave land in distinct banks)
//   - no ds_bpermute per gather round, no xor-reduce epilogue: each 16-lane
//     group owns one bag end-to-end and stores its float4 column directly
//   - 10-deep unrolled index-read/gather pipeline (L=50 = 5 x 10, no tail)
// Prediction: dur 326 -> ~280-300 if per-wave overhead mattered; unchanged if
// we are at the random-gather DRAM efficiency wall.

constexpr int kBagsPerBlock = 16;  // 256 threads = 4 waves x 4 bags/wave
constexpr int kMaxFast = 64;       // fast path when bag count <= 64 (L=50 here)

__global__ __launch_bounds__(256) void FreqAwareEmbedding_kernel(
    const int* __restrict__ indices,    // [T]
    const int* __restrict__ offsets,    // [B]
    const float4* __restrict__ weight4, // [V*16] (V x 64 fp32 as float4)
    float4* __restrict__ out4,          // [B*16]
    int B, int T)
{
    // +1 pad: group bases differ by 65 words -> the 4 concurrent broadcast
    // reads of a wave hit 4 distinct banks.
    __shared__ int sidx[kBagsPerBlock][kMaxFast + 1];

    const int tid = threadIdx.x;
    const int grp = tid >> 4;       // 0..15: bag slot within block (16 threads each,
                                    // never straddles a 64-lane wave)
    const int col = tid & 15;       // float4 column within the 64-float row
    const int bag = blockIdx.x * kBagsPerBlock + grp;

    int start = 0, count = 0;
    if (bag < B) {
        start = offsets[bag];
        const int end = (bag + 1 < B) ? offsets[bag + 1] : T;
        count = end - start;
    }

    const bool fast = (count <= kMaxFast);  // count is uniform within the group
    if (fast) {
        // 16 lanes per bag cooperatively stage the bag's indices (coalesced
        // 64B segments per group).
        for (int j = col; j < count; j += 16)
            sidx[grp][j] = indices[start + j];
    }
    __syncthreads();

    float4 acc = make_float4(0.f, 0.f, 0.f, 0.f);

    if (fast) {
        const int* sp = sidx[grp];
        int j = 0;
        // 10-deep pipeline: 10 broadcast LDS reads, then 10 independent 256B
        // row-gathers in flight before the accumulate chain drains them.
        for (; j + 10 <= count; j += 10) {
            int id[10];
            #pragma unroll
            for (int u = 0; u < 10; ++u) id[u] = sp[j + u];
            #pragma unroll
            for (int u = 0; u < 10; ++u) {
                const float4 v = weight4[(size_t)id[u] * 16 + col];
                acc.x += v.x; acc.y += v.y; acc.z += v.z; acc.w += v.w;
            }
        }
        for (; j < count; ++j) {
            const float4 v = weight4[(size_t)sp[j] * 16 + col];
            acc.x += v.x; acc.y += v.y; acc.z += v.z; acc.w += v.w;
        }
    } else if (count > 0) {
        // Generic fallback (not hit for L=50): 16 lanes broadcast-load each
        // index straight from global.
        for (int j = 0; j < count; ++j) {
            const float4 v = weight4[(size_t)indices[start + j] * 16 + col];
            acc.x += v.x; acc.y += v.y; acc.z += v.z; acc.w += v.w;
        }
    }

    if (bag < B) {
        const float inv = 1.0f / (float)((count > 0) ? count : 1);
        acc.x *= inv; acc.y *= inv; acc.z *= inv; acc.w *= inv;
        out4[(size_t)bag * 16 + col] = acc;  // all 16 lanes store: 256B/bag, coalesced
    }
}

extern "C" void kernel_launch(void* const* d_in, const int* in_sizes, int n_in,
                              void* d_out, int out_size, void* d_ws, size_t ws_size,
                              hipStream_t stream) {
    const int*   indices = (const int*)d_in[0];
    const int*   offsets = (const int*)d_in[1];
    const float* weight  = (const float*)d_in[2];

    const int T = in_sizes[0];
    const int B = in_sizes[1];

    const int grid = (B + kBagsPerBlock - 1) / kBagsPerBlock;  // 1024 blocks

    FreqAwareEmbedding_kernel<<<grid, 256, 0, stream>>>(
        indices, offsets, (const float4*)weight, (float4*)d_out, B, T);
}